// Round 11
// baseline (103.046 us; speedup 1.0000x reference)
//
#include <hip/hip_runtime.h>
#include <hip/hip_cooperative_groups.h>

namespace cg = cooperative_groups;

#define NNODES 10000
#define NEDGES 4096
#define INF 300
#define OUTF 150
#define EPB 16                      // edges per tile
#define NGROUPS (NEDGES / EPB)      // 256
#define SPLITK 5                    // K split over INF; 300/5 = 60
#define KCHUNK (INF / SPLITK)       // 60
#define PHASES 3                    // burst phases of 20 rows
#define PROWS (KCHUNK / PHASES)     // 20 -> 40 burst regs live per phase
#define ETHREADS 192                // 3 waves; lanes 0..149 compute
#define GRID (NGROUPS * SPLITK)     // 1280 blocks
#define NTHREADS (GRID * ETHREADS)
#define NCU 256

#define SUMS_N (NNODES * OUTF)      // 1,500,000

// ---------------- fused cooperative kernel ----------------
// R10 lesson: an UNGUARDED cooperative launch deadlocked grid.sync() when
// co-residency wasn't met -> container death. This round the host checks
// hipOccupancyMaxActiveBlocksPerMultiprocessor before choosing this path.
__global__ __launch_bounds__(ETHREADS, 4) void fused_kernel(
    const float* __restrict__ feat, const float* __restrict__ efeat,
    const float* __restrict__ W, const float* __restrict__ B,
    const float* __restrict__ bias,
    const int* __restrict__ src, const int* __restrict__ dst,
    float* __restrict__ sums, float* __restrict__ cnts,
    float* __restrict__ out)
{
    cg::grid_group grid = cg::this_grid();

    __shared__ float hA[EPB][KCHUNK];
    __shared__ float s_ef[EPB];
    __shared__ int   s_src[EPB];
    __shared__ int   s_dst[EPB];

    const int tid  = threadIdx.x;
    const int gtid = blockIdx.x * ETHREADS + tid;

    // ---- Phase A: zero sums + cnts (contiguous in ws) ----
    for (int i = gtid; i < SUMS_N + NNODES; i += NTHREADS)
        sums[i] = 0.f;
    grid.sync();

    // ---- Phase B: per-edge matmul partials + atomic scatter ----
    {
        const int kc  = blockIdx.x / NGROUPS;
        const int grp = blockIdx.x - kc * NGROUPS;
        const int e0  = grp * EPB;
        const int k0  = kc * KCHUNK;

        if (tid < EPB) {
            const int e = e0 + tid;
            s_src[tid] = src[e];
            s_dst[tid] = dst[e];
            s_ef[tid]  = efeat[e];
        }
        __syncthreads();

        for (int q = tid; q < EPB * (KCHUNK / 4); q += ETHREADS) {
            const int el = q / (KCHUNK / 4);
            const int j4 = q - el * (KCHUNK / 4);
            *(float4*)&hA[el][4 * j4] =
                *(const float4*)(feat + (size_t)s_src[el] * INF + k0 + 4 * j4);
        }
        __syncthreads();

        if (tid < OUTF) {
            float accW[EPB], accB[EPB];
            #pragma unroll
            for (int e = 0; e < EPB; ++e) { accW[e] = 0.f; accB[e] = 0.f; }

            const float* Wc = W + (size_t)k0 * OUTF + tid;
            const float* Bc = B + (size_t)k0 * OUTF + tid;

            #pragma unroll
            for (int ph = 0; ph < PHASES; ++ph) {
                const int base = ph * PROWS;
                float wr[PROWS], br[PROWS];
                #pragma unroll
                for (int r = 0; r < PROWS; ++r) {
                    wr[r] = Wc[(size_t)(base + r) * OUTF];
                    br[r] = Bc[(size_t)(base + r) * OUTF];
                }
                __builtin_amdgcn_sched_barrier(0);
                #pragma unroll
                for (int i4 = 0; i4 < PROWS; i4 += 4) {
                    #pragma unroll
                    for (int e = 0; e < EPB; ++e) {
                        const float4 h = *(const float4*)&hA[e][base + i4];
                        accW[e] = fmaf(h.w, wr[i4 + 3], fmaf(h.z, wr[i4 + 2],
                                  fmaf(h.y, wr[i4 + 1], fmaf(h.x, wr[i4 + 0], accW[e]))));
                        accB[e] = fmaf(h.w, br[i4 + 3], fmaf(h.z, br[i4 + 2],
                                  fmaf(h.y, br[i4 + 1], fmaf(h.x, br[i4 + 0], accB[e]))));
                    }
                }
            }
            #pragma unroll
            for (int e = 0; e < EPB; ++e) {
                const float msg = fmaf(s_ef[e], accW[e], accB[e]);
                atomicAdd(&sums[(size_t)s_dst[e] * OUTF + tid], msg);
            }
        } else if (kc == 0 && tid < OUTF + EPB) {
            atomicAdd(&cnts[s_dst[tid - OUTF]], 1.0f);
        }
    }
    grid.sync();

    // ---- Phase C: mean + bias + relu ----
    for (int i = gtid; i < SUMS_N; i += NTHREADS) {
        const int n = i / OUTF;
        const int o = i - n * OUTF;
        const float c = cnts[n];
        const float m = sums[i] / fmaxf(c, 1.0f);
        const float v = m + bias[o];
        out[i] = v > 0.f ? v : 0.f;
    }
}

// ---------------- fallback path (proven R6 structure, ~101 us) ----------------
__global__ __launch_bounds__(ETHREADS, 4) void edge_msg_kernel(
    const float* __restrict__ feat, const float* __restrict__ efeat,
    const float* __restrict__ W, const float* __restrict__ B,
    const int* __restrict__ src, const int* __restrict__ dst,
    float* __restrict__ sums, float* __restrict__ cnts)
{
    __shared__ float hA[EPB][KCHUNK];
    __shared__ float s_ef[EPB];
    __shared__ int   s_src[EPB];
    __shared__ int   s_dst[EPB];

    const int tid = threadIdx.x;
    const int kc  = blockIdx.x / NGROUPS;
    const int grp = blockIdx.x - kc * NGROUPS;
    const int e0  = grp * EPB;
    const int k0  = kc * KCHUNK;

    if (tid < EPB) {
        const int e = e0 + tid;
        s_src[tid] = src[e];
        s_dst[tid] = dst[e];
        s_ef[tid]  = efeat[e];
    }
    __syncthreads();

    for (int q = tid; q < EPB * (KCHUNK / 4); q += ETHREADS) {
        const int el = q / (KCHUNK / 4);
        const int j4 = q - el * (KCHUNK / 4);
        *(float4*)&hA[el][4 * j4] =
            *(const float4*)(feat + (size_t)s_src[el] * INF + k0 + 4 * j4);
    }
    __syncthreads();

    if (tid < OUTF) {
        float accW[EPB], accB[EPB];
        #pragma unroll
        for (int e = 0; e < EPB; ++e) { accW[e] = 0.f; accB[e] = 0.f; }
        const float* Wc = W + (size_t)k0 * OUTF + tid;
        const float* Bc = B + (size_t)k0 * OUTF + tid;
        #pragma unroll
        for (int ph = 0; ph < PHASES; ++ph) {
            const int base = ph * PROWS;
            float wr[PROWS], br[PROWS];
            #pragma unroll
            for (int r = 0; r < PROWS; ++r) {
                wr[r] = Wc[(size_t)(base + r) * OUTF];
                br[r] = Bc[(size_t)(base + r) * OUTF];
            }
            __builtin_amdgcn_sched_barrier(0);
            #pragma unroll
            for (int i4 = 0; i4 < PROWS; i4 += 4) {
                #pragma unroll
                for (int e = 0; e < EPB; ++e) {
                    const float4 h = *(const float4*)&hA[e][base + i4];
                    accW[e] = fmaf(h.w, wr[i4 + 3], fmaf(h.z, wr[i4 + 2],
                              fmaf(h.y, wr[i4 + 1], fmaf(h.x, wr[i4 + 0], accW[e]))));
                    accB[e] = fmaf(h.w, br[i4 + 3], fmaf(h.z, br[i4 + 2],
                              fmaf(h.y, br[i4 + 1], fmaf(h.x, br[i4 + 0], accB[e]))));
                }
            }
        }
        #pragma unroll
        for (int e = 0; e < EPB; ++e) {
            const float msg = fmaf(s_ef[e], accW[e], accB[e]);
            atomicAdd(&sums[(size_t)s_dst[e] * OUTF + tid], msg);
        }
    } else if (kc == 0 && tid < OUTF + EPB) {
        atomicAdd(&cnts[s_dst[tid - OUTF]], 1.0f);
    }
}

__global__ __launch_bounds__(256) void finalize_kernel(
    const float* __restrict__ sums, const float* __restrict__ cnts,
    const float* __restrict__ bias, float* __restrict__ out)
{
    const int idx = blockIdx.x * blockDim.x + threadIdx.x;
    if (idx < SUMS_N) {
        const int n = idx / OUTF;
        const int o = idx - n * OUTF;
        const float c = cnts[n];
        const float m = sums[idx] / fmaxf(c, 1.0f);
        const float v = m + bias[o];
        out[idx] = v > 0.f ? v : 0.f;
    }
}

extern "C" void kernel_launch(void* const* d_in, const int* in_sizes, int n_in,
                              void* d_out, int out_size, void* d_ws, size_t ws_size,
                              hipStream_t stream) {
    const float* feat  = (const float*)d_in[0];
    const float* efeat = (const float*)d_in[1];
    const float* W     = (const float*)d_in[2];
    const float* B     = (const float*)d_in[3];
    const float* bias  = (const float*)d_in[4];
    const int*   src   = (const int*)d_in[5];
    const int*   dst   = (const int*)d_in[6];
    float* out  = (float*)d_out;

    float* sums = (float*)d_ws;                 // [SUMS_N]
    float* cnts = sums + SUMS_N;                // [NNODES] (contiguous with sums)

    // Guard the cooperative launch: only take it if the runtime confirms all
    // GRID blocks are simultaneously resident (otherwise grid.sync deadlocks
    // -> R10's container death). Query is host-only & deterministic: same
    // path every call, graph-capture-safe.
    int maxBlocksPerCU = 0;
    hipError_t err = hipOccupancyMaxActiveBlocksPerMultiprocessor(
        &maxBlocksPerCU, (const void*)fused_kernel, ETHREADS, 0);

    hipError_t launch_err = hipErrorUnknown;
    if (err == hipSuccess && maxBlocksPerCU * NCU >= GRID) {
        void* args[] = { (void*)&feat, (void*)&efeat, (void*)&W, (void*)&B,
                         (void*)&bias, (void*)&src, (void*)&dst,
                         (void*)&sums, (void*)&cnts, (void*)&out };
        launch_err = hipLaunchCooperativeKernel((void*)fused_kernel, dim3(GRID),
                                                dim3(ETHREADS), args, 0, stream);
    }
    if (launch_err != hipSuccess) {
        // Fallback: proven 3-kernel path (R6 structure).
        hipMemsetAsync(d_ws, 0, (size_t)(SUMS_N + NNODES) * sizeof(float), stream);
        edge_msg_kernel<<<GRID, ETHREADS, 0, stream>>>(
            feat, efeat, W, B, src, dst, sums, cnts);
        finalize_kernel<<<(SUMS_N + 255) / 256, 256, 0, stream>>>(
            sums, cnts, bias, out);
    }
}